// Round 6
// baseline (415.331 us; speedup 1.0000x reference)
//
#include <hip/hip_runtime.h>
#include <math.h>

// ContextualNeuronPool: B=2,S=2048,K=8,POOL=512,DM=1024,DFF=4096,MD=64
// f32 inputs/outputs; internal GEMMs in bf16 MFMA.
#define T_    4096   // B*S tokens
#define K_    8
#define POOL_ 512
#define DM_   1024
#define DFF_  4096
#define MD_   64
#define KC_   576    // 512 (pool) + 64 (mod) combined contraction dim

typedef __bf16 bf16x8 __attribute__((ext_vector_type(8)));
typedef __bf16 bf16x4 __attribute__((ext_vector_type(4)));
typedef float  f32x4  __attribute__((ext_vector_type(4)));

typedef __attribute__((address_space(1))) const void g_void;
typedef __attribute__((address_space(3))) void s_void;

__device__ __forceinline__ void async_ld16(const void* g, void* s) {
    __builtin_amdgcn_global_load_lds((g_void*)g, (s_void*)s, 16, 0, 0);
}
__device__ __forceinline__ float gelu_exact(float g) {
    return 0.5f * g * (1.f + erff(g * 0.70710678118654752f));
}
__device__ __forceinline__ bf16x4 cvt4(float4 v) {
    bf16x4 o;
    o[0] = (__bf16)v.x; o[1] = (__bf16)v.y; o[2] = (__bf16)v.z; o[3] = (__bf16)v.w;
    return o;
}
__device__ __forceinline__ bf16x8 cvt8(float4 a, float4 b) {
    bf16x8 o;
    o[0] = (__bf16)a.x; o[1] = (__bf16)a.y; o[2] = (__bf16)a.z; o[3] = (__bf16)a.w;
    o[4] = (__bf16)b.x; o[5] = (__bf16)b.y; o[6] = (__bf16)b.z; o[7] = (__bf16)b.w;
    return o;
}

// ---------------------------------------------------------------------------
// Binning: counting sort of the 32768 (token,k) pairs by pool index.
// ---------------------------------------------------------------------------
__global__ __launch_bounds__(256) void k_hist(const int* __restrict__ sel,
                                              int* __restrict__ counts) {
    int i = blockIdx.x * 256 + threadIdx.x;
    if (i < T_ * K_) atomicAdd(&counts[sel[i]], 1);
}

__global__ __launch_bounds__(512) void k_scan(const int* __restrict__ counts,
                                              int* __restrict__ offsets,
                                              int* __restrict__ cursor) {
    __shared__ int s[512];
    const int t = threadIdx.x;
    const int c = counts[t];
    s[t] = c;
    __syncthreads();
    for (int d = 1; d < 512; d <<= 1) {
        int v = (t >= d) ? s[t - d] : 0;
        __syncthreads();
        s[t] += v;
        __syncthreads();
    }
    offsets[t] = s[t] - c;
    cursor[t]  = s[t] - c;
    if (t == 511) offsets[512] = s[511];
}

__global__ __launch_bounds__(256) void k_scatter(const int* __restrict__ sel,
                                                 int* __restrict__ cursor,
                                                 int* __restrict__ bucket,
                                                 int* __restrict__ rank) {
    int i = blockIdx.x * 256 + threadIdx.x;
    if (i < T_ * K_) {
        int p = sel[i];
        int pos = atomicAdd(&cursor[p], 1);
        bucket[pos] = i;
        rank[i] = pos;
    }
}

// ---------------------------------------------------------------------------
// K0: f32 -> bf16 convert (used for w2 and x). n16 = n/16.
// ---------------------------------------------------------------------------
__global__ __launch_bounds__(256) void k_cvt(const float* __restrict__ src,
                                             __bf16* __restrict__ dst, int n16) {
    int i = blockIdx.x * 256 + threadIdx.x;
    if (i >= n16) return;
    const float4* s = (const float4*)src + (long)i * 4;
    float4 a = s[0], b = s[1], c = s[2], d = s[3];
    bf16x8 o0 = cvt8(a, b), o1 = cvt8(c, d);
    bf16x8* dp = (bf16x8*)dst + (long)i * 2;
    dp[0] = o0; dp[1] = o1;
}

// ---------------------------------------------------------------------------
// K1 v7: W-in-LDS (one-shot, coalesced), X direct-from-global, NO barriers in
//   the main loop. Block (p, kh): stages its 64x256-f32 W sub-tile once into
//   padded LDS [64][264], then waves run free. Partial-Y to 4 disjoint
//   buffers (summed in k_wdense). ~35 KB LDS -> 4 blocks/CU.
// ---------------------------------------------------------------------------
__global__ __launch_bounds__(256) void k_selmod(
    const __bf16* __restrict__ xb, const float* __restrict__ cm_w,
    const int* __restrict__ bucket, const int* __restrict__ offsets,
    float* __restrict__ Y0, float* __restrict__ Y1,
    float* __restrict__ Y2, float* __restrict__ Y3)
{
    const int p   = blockIdx.x;
    const int kh  = blockIdx.y;               // k-slice: cols kh*256 .. +256
    const int off = offsets[p];
    int n = offsets[p + 1] - off;
    if (n <= 0) return;
    if (n > 256) n = 256;                     // safety cap (P(n>256) ~ 0)
    float* Y = (kh == 0) ? Y0 : (kh == 1) ? Y1 : (kh == 2) ? Y2 : Y3;

    const int tid  = threadIdx.x;
    const int wave = tid >> 6, lane = tid & 63;
    const int quad = lane >> 4, l15 = lane & 15;

    __shared__ int list[256];
    __shared__ __align__(16) __bf16 Wl[64][264];   // 33792 B

    // issue list gather FIRST so its latency hides under the W stream
    int lv = -1;
    if (tid < n) lv = bucket[off + tid] >> 3;

    // ---- stage W: 64 rows x 256 f32, once (each wave-instr = 1 KB row) ----
    {
        const int wr = tid >> 6;              // base row 0..3 (one per wave)
        const int wc = (tid & 63) * 4;        // f32 col 0..252 (lane-contig)
        const float* wsrc = cm_w + (long)(p * 64 + wr) * DM_ + kh * 256 + wc;
        float4 wv[16];
        #pragma unroll
        for (int j = 0; j < 16; ++j)
            wv[j] = *(const float4*)(wsrc + (long)j * 4 * DM_);
        #pragma unroll
        for (int j = 0; j < 16; ++j)
            *(bf16x4*)&Wl[wr + j * 4][wc] = cvt4(wv[j]);
    }
    if (tid < n) list[tid] = lv;
    __syncthreads();                          // the ONLY barrier

    const int nch = (n + 15) >> 4;
    for (int c = wave; c < nch; c += 4) {
        int row = c * 16 + l15; if (row >= n) row = n - 1;   // clamp: dup row
        const __bf16* xrow = xb + (long)list[row] * DM_ + kh * 256 + quad * 8;

        f32x4 a0 = {}, a1 = {}, a2 = {}, a3 = {};
        #pragma unroll
        for (int ks = 0; ks < 8; ++ks) {
            const bf16x8 afr = *(const bf16x8*)(xrow + ks * 32);
            const bf16x8 b0 = *(const bf16x8*)&Wl[ 0 + l15][ks * 32 + quad * 8];
            const bf16x8 b1 = *(const bf16x8*)&Wl[16 + l15][ks * 32 + quad * 8];
            const bf16x8 b2 = *(const bf16x8*)&Wl[32 + l15][ks * 32 + quad * 8];
            const bf16x8 b3 = *(const bf16x8*)&Wl[48 + l15][ks * 32 + quad * 8];
            a0 = __builtin_amdgcn_mfma_f32_16x16x32_bf16(afr, b0, a0, 0, 0, 0);
            a1 = __builtin_amdgcn_mfma_f32_16x16x32_bf16(afr, b1, a1, 0, 0, 0);
            a2 = __builtin_amdgcn_mfma_f32_16x16x32_bf16(afr, b2, a2, 0, 0, 0);
            a3 = __builtin_amdgcn_mfma_f32_16x16x32_bf16(afr, b3, a3, 0, 0, 0);
        }
        // C/D layout: out row = c*16 + quad*4 + r, col = m*16 + l15
        #pragma unroll
        for (int r = 0; r < 4; ++r) {
            const int prow = c * 16 + quad * 4 + r;
            if (prow < n) {
                float* yr = Y + (long)(off + prow) * MD_ + l15;
                yr[ 0] = a0[r];
                yr[16] = a1[r];
                yr[32] = a2[r];
                yr[48] = a3[r];
            }
        }
    }
}

// ---------------------------------------------------------------------------
// K2a: build dense combine matrix Wd[4096][576] bf16.
// ---------------------------------------------------------------------------
__global__ __launch_bounds__(256) void k_wdense(
    const float* __restrict__ Y0, const float* __restrict__ Y1,
    const float* __restrict__ Y2, const float* __restrict__ Y3,
    const int* __restrict__ sel, const int* __restrict__ rank,
    const float* __restrict__ pw, const float* __restrict__ cm_b,
    __bf16* __restrict__ Wd)
{
    const int tid = threadIdx.x;
    const int tt = tid >> 6, m = tid & 63;
    const int t = blockIdx.x * 4 + tt;
    __shared__ float w_s[4][8];
    __shared__ int   sidx[4][8];
    __shared__ int   rnk[4][8];
    __shared__ __align__(16) __bf16 row[4][KC_];

    if (m < 8) {
        w_s[tt][m]  = pw[t * 8 + m];
        sidx[tt][m] = sel[t * 8 + m];
        rnk[tt][m]  = rank[t * 8 + m];
    }
    __syncthreads();
    if (m == 0) {
        float mx = w_s[tt][0];
        #pragma unroll
        for (int k = 1; k < 8; ++k) mx = fmaxf(mx, w_s[tt][k]);
        float sum = 0.f;
        #pragma unroll
        for (int k = 0; k < 8; ++k) { float e = expf(w_s[tt][k] - mx); w_s[tt][k] = e; sum += e; }
        float inv = 1.f / sum;
        #pragma unroll
        for (int k = 0; k < 8; ++k) w_s[tt][k] *= inv;
    }
    __syncthreads();
    *(uint4*)&row[tt][m * 8] = make_uint4(0, 0, 0, 0);   // zero cols 0..511
    {
        float a = 0.f;
        #pragma unroll
        for (int k = 0; k < 8; ++k) {
            const long yb = (long)rnk[tt][k] * MD_ + m;
            float y = cm_b[sidx[tt][k] * 64 + m] + Y0[yb] + Y1[yb] + Y2[yb] + Y3[yb];
            a += w_s[tt][k] * y;
        }
        row[tt][512 + m] = (__bf16)a;
    }
    __syncthreads();
    if (m == 0) {
        #pragma unroll
        for (int k = 0; k < 8; ++k) {
            int c = sidx[tt][k];
            row[tt][c] = (__bf16)((float)row[tt][c] + w_s[tt][k]);  // dup-safe
        }
    }
    __syncthreads();
    const uint4* src = (const uint4*)&row[0][0];
    uint4* dst = (uint4*)(Wd + (long)blockIdx.x * 4 * KC_);
    for (int e = tid; e < 4 * KC_ * 2 / 16; e += 256) dst[e] = src[e];
}

// ---------------------------------------------------------------------------
// K2b: P[4096][576] bf16: P[f][c] = bp[c][f] (c<512) / adj[c-512][f].
// ---------------------------------------------------------------------------
__global__ __launch_bounds__(256) void k_buildP(
    const float* __restrict__ bp, const float* __restrict__ adj,
    __bf16* __restrict__ P)
{
    __shared__ __bf16 tile[64][72];
    const int tid = threadIdx.x;
    const int bx = blockIdx.x, f0 = blockIdx.y * 64;
    const float* src = (bx < 8) ? (bp + (long)bx * 64 * DFF_) : adj;
    for (int e = tid; e < 4096; e += 256) {
        int f = e & 63, c = e >> 6;
        tile[c][f] = (__bf16)src[(long)c * DFF_ + f0 + f];
    }
    __syncthreads();
    const int c0 = bx * 64;
    for (int e = tid; e < 4096; e += 256) {
        int c = e & 63, f = e >> 6;
        P[(long)(f0 + f) * KC_ + c0 + c] = tile[c][f];
    }
}

// ---------------------------------------------------------------------------
// K2c v2: act = gelu( Wd[4096][576] @ P[4096][576]^T ), bf16 out.
//   2-phase double-buffered: STAGE(next tile) issued BEFORE compute(current),
//   one barrier per K-tile -> loads fly under the 16 MFMAs (T3-minimum).
//   LDS layout per buf: [128 rows][32 cols] (64 B row stride, conflict-free).
// ---------------------------------------------------------------------------
__global__ __launch_bounds__(256) void k_actgemm(
    const __bf16* __restrict__ A, const __bf16* __restrict__ Bw,
    __bf16* __restrict__ act)
{
    __shared__ __align__(16) __bf16 sA[2 * 128 * 32];
    __shared__ __align__(16) __bf16 sB[2 * 128 * 32];
    const int tid  = threadIdx.x;
    const int tm   = blockIdx.y * 128, tn = blockIdx.x * 128;
    const int wave = tid >> 6, lane = tid & 63, quad = lane >> 4, l15 = lane & 15;
    const int wm   = (wave >> 1) * 64, wn = (wave & 1) * 64;

    f32x4 acc[4][4] = {};

    const int e    = tid * 8;
    const int srow = e >> 5;              // row within 64-row half
    const int scol = e & 31;
    const __bf16* agp0 = A  + ((long)(tm + srow)      * KC_ + scol);
    const __bf16* agp1 = A  + ((long)(tm + 64 + srow) * KC_ + scol);
    const __bf16* bgp0 = Bw + ((long)(tn + srow)      * KC_ + scol);
    const __bf16* bgp1 = Bw + ((long)(tn + 64 + srow) * KC_ + scol);

    const int NT = KC_ / 32;              // 18 K-tiles

    // prologue: stage tile 0 into buf 0
    async_ld16(agp0, (void*)(sA + e));
    async_ld16(agp1, (void*)(sA + 2048 + e));
    async_ld16(bgp0, (void*)(sB + e));
    async_ld16(bgp1, (void*)(sB + 2048 + e));
    __syncthreads();

    int cur = 0;
    for (int t = 0; t < NT; ++t) {
        if (t + 1 < NT) {                 // stage next tile EARLY (other buf)
            const int kk = (t + 1) * 32;
            const int nb = (cur ^ 1) * 4096;
            async_ld16(agp0 + kk, (void*)(sA + nb + e));
            async_ld16(agp1 + kk, (void*)(sA + nb + 2048 + e));
            async_ld16(bgp0 + kk, (void*)(sB + nb + e));
            async_ld16(bgp1 + kk, (void*)(sB + nb + 2048 + e));
        }
        const int cb = cur * 4096;
        bf16x8 af[4], bf[4];
        #pragma unroll
        for (int i = 0; i < 4; ++i)
            af[i] = *(const bf16x8*)(sA + cb + (wm + i * 16 + l15) * 32 + quad * 8);
        #pragma unroll
        for (int j = 0; j < 4; ++j)
            bf[j] = *(const bf16x8*)(sB + cb + (wn + j * 16 + l15) * 32 + quad * 8);
        #pragma unroll
        for (int i = 0; i < 4; ++i)
            #pragma unroll
            for (int j = 0; j < 4; ++j)
                acc[i][j] = __builtin_amdgcn_mfma_f32_16x16x32_bf16(af[i], bf[j], acc[i][j], 0, 0, 0);
        __syncthreads();                  // drains staged loads + syncs reads
        cur ^= 1;
    }

    #pragma unroll
    for (int j = 0; j < 4; ++j) {
        const int col = tn + wn + j * 16 + l15;
        #pragma unroll
        for (int i = 0; i < 4; ++i) {
            const int row = tm + wm + i * 16 + quad * 4;
            #pragma unroll
            for (int r = 0; r < 4; ++r)
                act[(long)(row + r) * DFF_ + col] = (__bf16)gelu_exact(acc[i][j][r]);
        }
    }
}

// ---------------------------------------------------------------------------
// K3 v2: out[4096][1024] = act @ w2bf^T + w2_b. BK=64, 2-phase dbuf.
//   Per buf: 2 chunks x [128 rows][32 cols] (conflict-free 64 B row stride).
//   STAGE(next) before compute(current); one barrier per K-tile.
// ---------------------------------------------------------------------------
__global__ __launch_bounds__(256) void k_outgemm(
    const __bf16* __restrict__ A, const __bf16* __restrict__ Bw,
    const float* __restrict__ bias, float* __restrict__ out)
{
    __shared__ __align__(16) __bf16 sA[2 * 2 * 128 * 32];   // 32 KB
    __shared__ __align__(16) __bf16 sB[2 * 2 * 128 * 32];   // 32 KB
    const int tid  = threadIdx.x;
    const int tm   = blockIdx.y * 128, tn = blockIdx.x * 128;
    const int wave = tid >> 6, lane = tid & 63, quad = lane >> 4, l15 = lane & 15;
    const int wm   = (wave >> 1) * 64, wn = (wave & 1) * 64;

    f32x4 acc[4][4] = {};

    const int e  = tid * 8;
    const int r0 = e >> 5;                // row within 64-row half
    const int cc = e & 31;

    const int NT = DFF_ / 64;             // 64 K-tiles

    // prologue: stage tile 0 into buf 0
    #pragma unroll
    for (int s = 0; s < 2; ++s)
        #pragma unroll
        for (int q = 0; q < 2; ++q) {
            async_ld16(A  + (long)(tm + q * 64 + r0) * DFF_ + s * 32 + cc,
                       (void*)(sA + s * 4096 + q * 2048 + e));
            async_ld16(Bw + (long)(tn + q * 64 + r0) * DFF_ + s * 32 + cc,
                       (void*)(sB + s * 4096 + q * 2048 + e));
        }
    __syncthreads();

    int cur = 0;
    for (int t = 0; t < NT; ++t) {
        if (t + 1 < NT) {                 // stage next tile EARLY (other buf)
            const int kk = (t + 1) * 64;
            const int nb = (cur ^ 1) * 8192;
            #pragma unroll
            for (int s = 0; s < 2; ++s)
                #pragma unroll
                for (int q = 0; q < 2; ++q) {
                    async_ld16(A  + (long)(tm + q * 64 + r0) * DFF_ + kk + s * 32 + cc,
                               (void*)(sA + nb + s * 4096 + q * 2048 + e));
                    async_ld16(Bw + (long)(tn + q * 64 + r0) * DFF_ + kk + s * 32 + cc,
                               (void*)(sB + nb + s * 4096 + q * 2048 + e));
                }
        }
        const int cb = cur * 8192;
        #pragma unroll
        for (int s = 0; s < 2; ++s) {
            bf16x8 af[4], bf[4];
            #pragma unroll
            for (int i = 0; i < 4; ++i)
                af[i] = *(const bf16x8*)(sA + cb + s * 4096 + (wm + i * 16 + l15) * 32 + quad * 8);
            #pragma unroll
            for (int j = 0; j < 4; ++j)
                bf[j] = *(const bf16x8*)(sB + cb + s * 4096 + (wn + j * 16 + l15) * 32 + quad * 8);
            #pragma unroll
            for (int i = 0; i < 4; ++i)
                #pragma unroll
                for (int j = 0; j < 4; ++j)
                    acc[i][j] = __builtin_amdgcn_mfma_f32_16x16x32_bf16(af[i], bf[j], acc[i][j], 0, 0, 0);
        }
        __syncthreads();                  // drains staged loads + syncs reads
        cur ^= 1;
    }

    #pragma unroll
    for (int j = 0; j < 4; ++j) {
        const int col = tn + wn + j * 16 + l15;
        const float bj = bias[col];
        #pragma unroll
        for (int i = 0; i < 4; ++i) {
            const int row = tm + wm + i * 16 + quad * 4;
            #pragma unroll
            for (int r = 0; r < 4; ++r)
                out[(long)(row + r) * 1024 + col] = acc[i][j][r] + bj;
        }
    }
}

// ---------------------------------------------------------------------------
extern "C" void kernel_launch(void* const* d_in, const int* in_sizes, int n_in,
                              void* d_out, int out_size, void* d_ws, size_t ws_size,
                              hipStream_t stream) {
    const float* x    = (const float*)d_in[0];
    const int*   sel  = (const int*)  d_in[1];
    const float* pw   = (const float*)d_in[2];
    const float* bp   = (const float*)d_in[3];
    const float* cm_w = (const float*)d_in[4];
    const float* cm_b = (const float*)d_in[5];
    const float* adj  = (const float*)d_in[6];
    const float* w2   = (const float*)d_in[7];
    const float* w2b  = (const float*)d_in[8];
    float* out = (float*)d_out;

    // ws: [0,8M) x_bf | [8M,32M) Yp1..Yp3 (both dead once act is written)
    //     [0,32M) act | [32M,37M) P | [37M,45M) w2bf | [45M,..) bins
    char* ws = (char*)d_ws;
    __bf16* x_bf = (__bf16*)ws;
    __bf16* act  = (__bf16*)ws;
    float*  Yp1  = (float*)(ws + (size_t) 8 * 1024 * 1024);
    float*  Yp2  = (float*)(ws + (size_t)16 * 1024 * 1024);
    float*  Yp3  = (float*)(ws + (size_t)24 * 1024 * 1024);
    __bf16* P    = (__bf16*)(ws + (size_t)32 * 1024 * 1024);
    __bf16* w2bf = (__bf16*)(ws + (size_t)37 * 1024 * 1024);
    char*  bins  = ws + (size_t)45 * 1024 * 1024;
    int* bucket  = (int*)bins;                 // 131072 B
    int* rank    = (int*)(bins + 131072);      // 131072 B
    int* counts  = (int*)(bins + 262144);      // 2048 B
    int* cursor  = (int*)(bins + 264192);      // 2048 B
    int* offsets = (int*)(bins + 266240);      // 2052 B

    // d_out staging (consumed before k_outgemm): Yp0 f32 8M | Wd 4.72M
    float*  Yp0 = (float*)d_out;
    __bf16* Wd  = (__bf16*)((char*)d_out + (size_t)8 * 1024 * 1024);

    hipMemsetAsync(counts, 0, 4096, stream);   // counts + cursor
    k_hist   <<<128, 256, 0, stream>>>(sel, counts);
    k_scan   <<<1,   512, 0, stream>>>(counts, offsets, cursor);
    k_scatter<<<128, 256, 0, stream>>>(sel, cursor, bucket, rank);
    k_cvt    <<<1024, 256, 0, stream>>>(x, x_bf, T_ * DM_ / 16);
    k_selmod <<<dim3(POOL_, 4), 256, 0, stream>>>(x_bf, cm_w, bucket, offsets,
                                                  Yp0, Yp1, Yp2, Yp3);
    k_wdense <<<T_ / 4, 256, 0, stream>>>(Yp0, Yp1, Yp2, Yp3, sel, rank, pw, cm_b, Wd);
    k_buildP <<<dim3(9, 64), 256, 0, stream>>>(bp, adj, P);
    k_cvt    <<<1024, 256, 0, stream>>>(w2, w2bf, DM_ * DFF_ / 16);
    k_actgemm<<<dim3(DFF_ / 128, T_ / 128), 256, 0, stream>>>(Wd, P, act);
    k_outgemm<<<dim3(DM_ / 128, T_ / 128), 256, 0, stream>>>(act, w2bf, w2b, out);
}

// Round 9
// 398.807 us; speedup vs baseline: 1.0414x; 1.0414x over previous
//
#include <hip/hip_runtime.h>
#include <math.h>

// ContextualNeuronPool: B=2,S=2048,K=8,POOL=512,DM=1024,DFF=4096,MD=64
// f32 inputs/outputs; internal GEMMs in bf16 MFMA.
#define T_    4096   // B*S tokens
#define K_    8
#define POOL_ 512
#define DM_   1024
#define DFF_  4096
#define MD_   64
#define KC_   576    // 512 (pool) + 64 (mod) combined contraction dim

typedef __bf16 bf16x8 __attribute__((ext_vector_type(8)));
typedef __bf16 bf16x4 __attribute__((ext_vector_type(4)));
typedef float  f32x4  __attribute__((ext_vector_type(4)));

typedef __attribute__((address_space(1))) const void g_void;
typedef __attribute__((address_space(3))) void s_void;

__device__ __forceinline__ void async_ld16(const void* g, void* s) {
    __builtin_amdgcn_global_load_lds((g_void*)g, (s_void*)s, 16, 0, 0);
}
__device__ __forceinline__ float gelu_exact(float g) {
    return 0.5f * g * (1.f + erff(g * 0.70710678118654752f));
}
__device__ __forceinline__ bf16x4 cvt4(float4 v) {
    bf16x4 o;
    o[0] = (__bf16)v.x; o[1] = (__bf16)v.y; o[2] = (__bf16)v.z; o[3] = (__bf16)v.w;
    return o;
}
__device__ __forceinline__ bf16x8 cvt8(float4 a, float4 b) {
    bf16x8 o;
    o[0] = (__bf16)a.x; o[1] = (__bf16)a.y; o[2] = (__bf16)a.z; o[3] = (__bf16)a.w;
    o[4] = (__bf16)b.x; o[5] = (__bf16)b.y; o[6] = (__bf16)b.z; o[7] = (__bf16)b.w;
    return o;
}

// ---------------------------------------------------------------------------
// Binning: counting sort of the 32768 (token,k) pairs by pool index.
// ---------------------------------------------------------------------------
__global__ __launch_bounds__(256) void k_hist(const int* __restrict__ sel,
                                              int* __restrict__ counts) {
    int i = blockIdx.x * 256 + threadIdx.x;
    if (i < T_ * K_) atomicAdd(&counts[sel[i]], 1);
}

__global__ __launch_bounds__(512) void k_scan(const int* __restrict__ counts,
                                              int* __restrict__ offsets,
                                              int* __restrict__ cursor) {
    __shared__ int s[512];
    const int t = threadIdx.x;
    const int c = counts[t];
    s[t] = c;
    __syncthreads();
    for (int d = 1; d < 512; d <<= 1) {
        int v = (t >= d) ? s[t - d] : 0;
        __syncthreads();
        s[t] += v;
        __syncthreads();
    }
    offsets[t] = s[t] - c;
    cursor[t]  = s[t] - c;
    if (t == 511) offsets[512] = s[511];
}

__global__ __launch_bounds__(256) void k_scatter(const int* __restrict__ sel,
                                                 int* __restrict__ cursor,
                                                 int* __restrict__ bucket,
                                                 int* __restrict__ rank) {
    int i = blockIdx.x * 256 + threadIdx.x;
    if (i < T_ * K_) {
        int p = sel[i];
        int pos = atomicAdd(&cursor[p], 1);
        bucket[pos] = i;
        rank[i] = pos;
    }
}

// ---------------------------------------------------------------------------
// K0: f32 -> bf16 convert (used for w2 and x). n16 = n/16.
// ---------------------------------------------------------------------------
__global__ __launch_bounds__(256) void k_cvt(const float* __restrict__ src,
                                             __bf16* __restrict__ dst, int n16) {
    int i = blockIdx.x * 256 + threadIdx.x;
    if (i >= n16) return;
    const float4* s = (const float4*)src + (long)i * 4;
    float4 a = s[0], b = s[1], c = s[2], d = s[3];
    bf16x8 o0 = cvt8(a, b), o1 = cvt8(c, d);
    bf16x8* dp = (bf16x8*)dst + (long)i * 2;
    dp[0] = o0; dp[1] = o1;
}

// ---------------------------------------------------------------------------
// K1 v7 (round-5 form, known-good): W-in-LDS (one-shot, coalesced), X direct
//   from global, NO barriers in the main loop. ~35 KB LDS -> 4 blocks/CU.
// ---------------------------------------------------------------------------
__global__ __launch_bounds__(256) void k_selmod(
    const __bf16* __restrict__ xb, const float* __restrict__ cm_w,
    const int* __restrict__ bucket, const int* __restrict__ offsets,
    float* __restrict__ Y0, float* __restrict__ Y1,
    float* __restrict__ Y2, float* __restrict__ Y3)
{
    const int p   = blockIdx.x;
    const int kh  = blockIdx.y;               // k-slice: cols kh*256 .. +256
    const int off = offsets[p];
    int n = offsets[p + 1] - off;
    if (n <= 0) return;
    if (n > 256) n = 256;                     // safety cap (P(n>256) ~ 0)
    float* Y = (kh == 0) ? Y0 : (kh == 1) ? Y1 : (kh == 2) ? Y2 : Y3;

    const int tid  = threadIdx.x;
    const int wave = tid >> 6, lane = tid & 63;
    const int quad = lane >> 4, l15 = lane & 15;

    __shared__ int list[256];
    __shared__ __align__(16) __bf16 Wl[64][264];   // 33792 B

    // ---- stage W: 64 rows x 256 f32, once (each wave-instr = 1 KB row) ----
    {
        const int wr = tid >> 6;              // base row 0..3 (one per wave)
        const int wc = (tid & 63) * 4;        // f32 col 0..252 (lane-contig)
        const float* wsrc = cm_w + (long)(p * 64 + wr) * DM_ + kh * 256 + wc;
        float4 wv[16];
        #pragma unroll
        for (int j = 0; j < 16; ++j)
            wv[j] = *(const float4*)(wsrc + (long)j * 4 * DM_);
        #pragma unroll
        for (int j = 0; j < 16; ++j)
            *(bf16x4*)&Wl[wr + j * 4][wc] = cvt4(wv[j]);
    }
    for (int i = tid; i < n; i += 256) list[i] = bucket[off + i] >> 3;
    __syncthreads();                          // the ONLY barrier

    const int nch = (n + 15) >> 4;
    for (int c = wave; c < nch; c += 4) {
        int row = c * 16 + l15; if (row >= n) row = n - 1;   // clamp: dup row
        const __bf16* xrow = xb + (long)list[row] * DM_ + kh * 256 + quad * 8;

        f32x4 a0 = {}, a1 = {}, a2 = {}, a3 = {};
        #pragma unroll
        for (int ks = 0; ks < 8; ++ks) {
            const bf16x8 afr = *(const bf16x8*)(xrow + ks * 32);
            const bf16x8 b0 = *(const bf16x8*)&Wl[ 0 + l15][ks * 32 + quad * 8];
            const bf16x8 b1 = *(const bf16x8*)&Wl[16 + l15][ks * 32 + quad * 8];
            const bf16x8 b2 = *(const bf16x8*)&Wl[32 + l15][ks * 32 + quad * 8];
            const bf16x8 b3 = *(const bf16x8*)&Wl[48 + l15][ks * 32 + quad * 8];
            a0 = __builtin_amdgcn_mfma_f32_16x16x32_bf16(afr, b0, a0, 0, 0, 0);
            a1 = __builtin_amdgcn_mfma_f32_16x16x32_bf16(afr, b1, a1, 0, 0, 0);
            a2 = __builtin_amdgcn_mfma_f32_16x16x32_bf16(afr, b2, a2, 0, 0, 0);
            a3 = __builtin_amdgcn_mfma_f32_16x16x32_bf16(afr, b3, a3, 0, 0, 0);
        }
        // C/D layout: out row = c*16 + quad*4 + r, col = m*16 + l15
        #pragma unroll
        for (int r = 0; r < 4; ++r) {
            const int prow = c * 16 + quad * 4 + r;
            if (prow < n) {
                float* yr = Y + (long)(off + prow) * MD_ + l15;
                yr[ 0] = a0[r];
                yr[16] = a1[r];
                yr[32] = a2[r];
                yr[48] = a3[r];
            }
        }
    }
}

// ---------------------------------------------------------------------------
// K2a: build dense combine matrix Wd[4096][576] bf16.
// ---------------------------------------------------------------------------
__global__ __launch_bounds__(256) void k_wdense(
    const float* __restrict__ Y0, const float* __restrict__ Y1,
    const float* __restrict__ Y2, const float* __restrict__ Y3,
    const int* __restrict__ sel, const int* __restrict__ rank,
    const float* __restrict__ pw, const float* __restrict__ cm_b,
    __bf16* __restrict__ Wd)
{
    const int tid = threadIdx.x;
    const int tt = tid >> 6, m = tid & 63;
    const int t = blockIdx.x * 4 + tt;
    __shared__ float w_s[4][8];
    __shared__ int   sidx[4][8];
    __shared__ int   rnk[4][8];
    __shared__ __align__(16) __bf16 row[4][KC_];

    if (m < 8) {
        w_s[tt][m]  = pw[t * 8 + m];
        sidx[tt][m] = sel[t * 8 + m];
        rnk[tt][m]  = rank[t * 8 + m];
    }
    __syncthreads();
    if (m == 0) {
        float mx = w_s[tt][0];
        #pragma unroll
        for (int k = 1; k < 8; ++k) mx = fmaxf(mx, w_s[tt][k]);
        float sum = 0.f;
        #pragma unroll
        for (int k = 0; k < 8; ++k) { float e = expf(w_s[tt][k] - mx); w_s[tt][k] = e; sum += e; }
        float inv = 1.f / sum;
        #pragma unroll
        for (int k = 0; k < 8; ++k) w_s[tt][k] *= inv;
    }
    __syncthreads();
    *(uint4*)&row[tt][m * 8] = make_uint4(0, 0, 0, 0);   // zero cols 0..511
    {
        float a = 0.f;
        #pragma unroll
        for (int k = 0; k < 8; ++k) {
            const long yb = (long)rnk[tt][k] * MD_ + m;
            float y = cm_b[sidx[tt][k] * 64 + m] + Y0[yb] + Y1[yb] + Y2[yb] + Y3[yb];
            a += w_s[tt][k] * y;
        }
        row[tt][512 + m] = (__bf16)a;
    }
    __syncthreads();
    if (m == 0) {
        #pragma unroll
        for (int k = 0; k < 8; ++k) {
            int c = sidx[tt][k];
            row[tt][c] = (__bf16)((float)row[tt][c] + w_s[tt][k]);  // dup-safe
        }
    }
    __syncthreads();
    const uint4* src = (const uint4*)&row[0][0];
    uint4* dst = (uint4*)(Wd + (long)blockIdx.x * 4 * KC_);
    for (int e = tid; e < 4 * KC_ * 2 / 16; e += 256) dst[e] = src[e];
}

// ---------------------------------------------------------------------------
// K2b: P[4096][576] bf16: P[f][c] = bp[c][f] (c<512) / adj[c-512][f].
// ---------------------------------------------------------------------------
__global__ __launch_bounds__(256) void k_buildP(
    const float* __restrict__ bp, const float* __restrict__ adj,
    __bf16* __restrict__ P)
{
    __shared__ __bf16 tile[64][72];
    const int tid = threadIdx.x;
    const int bx = blockIdx.x, f0 = blockIdx.y * 64;
    const float* src = (bx < 8) ? (bp + (long)bx * 64 * DFF_) : adj;
    for (int e = tid; e < 4096; e += 256) {
        int f = e & 63, c = e >> 6;
        tile[c][f] = (__bf16)src[(long)c * DFF_ + f0 + f];
    }
    __syncthreads();
    const int c0 = bx * 64;
    for (int e = tid; e < 4096; e += 256) {
        int c = e & 63, f = e >> 6;
        P[(long)(f0 + f) * KC_ + c0 + c] = tile[c][f];
    }
}

// ---------------------------------------------------------------------------
// K2c (round-5 form, known-good): act = gelu(Wd @ P^T), bf16 out.
//   grid 32x32 = 1024 blocks = 4/CU; inter-block overlap masks the drains.
// ---------------------------------------------------------------------------
__global__ __launch_bounds__(256) void k_actgemm(
    const __bf16* __restrict__ A, const __bf16* __restrict__ Bw,
    __bf16* __restrict__ act)
{
    __shared__ __align__(16) __bf16 sA[128 * 32];
    __shared__ __align__(16) __bf16 sB[128 * 32];
    const int tid  = threadIdx.x;
    const int tm   = blockIdx.y * 128, tn = blockIdx.x * 128;
    const int wave = tid >> 6, lane = tid & 63, quad = lane >> 4, l15 = lane & 15;
    const int wm   = (wave >> 1) * 64, wn = (wave & 1) * 64;

    f32x4 acc[4][4] = {};

    const int e    = tid * 8;
    const int srow = e >> 5;
    const int scol = e & 31;
    const __bf16* agp0 = A  + ((long)(tm + srow)      * KC_ + scol);
    const __bf16* agp1 = A  + ((long)(tm + 64 + srow) * KC_ + scol);
    const __bf16* bgp0 = Bw + ((long)(tn + srow)      * KC_ + scol);
    const __bf16* bgp1 = Bw + ((long)(tn + 64 + srow) * KC_ + scol);
    void* sa0 = (void*)(sA + e);
    void* sa1 = (void*)(sA + 2048 + e);
    void* sb0 = (void*)(sB + e);
    void* sb1 = (void*)(sB + 2048 + e);

    for (int kk = 0; kk < KC_; kk += 32) {
        async_ld16(agp0 + kk, sa0);
        async_ld16(agp1 + kk, sa1);
        async_ld16(bgp0 + kk, sb0);
        async_ld16(bgp1 + kk, sb1);
        __syncthreads();
        bf16x8 af[4], bf[4];
        #pragma unroll
        for (int i = 0; i < 4; ++i)
            af[i] = *(const bf16x8*)(sA + (wm + i * 16 + l15) * 32 + quad * 8);
        #pragma unroll
        for (int j = 0; j < 4; ++j)
            bf[j] = *(const bf16x8*)(sB + (wn + j * 16 + l15) * 32 + quad * 8);
        #pragma unroll
        for (int i = 0; i < 4; ++i)
            #pragma unroll
            for (int j = 0; j < 4; ++j)
                acc[i][j] = __builtin_amdgcn_mfma_f32_16x16x32_bf16(af[i], bf[j], acc[i][j], 0, 0, 0);
        __syncthreads();
    }

    #pragma unroll
    for (int j = 0; j < 4; ++j) {
        const int col = tn + wn + j * 16 + l15;
        #pragma unroll
        for (int i = 0; i < 4; ++i) {
            const int row = tm + wm + i * 16 + quad * 4;
            #pragma unroll
            for (int r = 0; r < 4; ++r)
                act[(long)(row + r) * DFF_ + col] = (__bf16)gelu_exact(acc[i][j][r]);
        }
    }
}

// ---------------------------------------------------------------------------
// K3 v4: out[4096][1024] = act @ w2bf^T + w2_b.
//   M-split for co-residency: tile 64(M)x128(N), grid (8,64) = 512 blocks =
//   2 blocks/CU (48 KB LDS each) -> the co-resident block's MFMAs cover this
//   block's vmcnt(0)+barrier drains (1-block/CU lockstep measured 85 us,
//   MfmaUtil 15%, Occ 10%). BK=64, 2-phase dbuf, prefetch issued BEFORE
//   compute. Per wave: acc[2][4], 16 MFMA per K-tile; fragment reads at the
//   ds_read_b128 bank minimum. (Same theory as failed-to-run v3; different
//   code path to dodge a possible source-specific container trigger.)
// ---------------------------------------------------------------------------
__global__ __launch_bounds__(256) void k_outgemm(
    const __bf16* __restrict__ A, const __bf16* __restrict__ Bw,
    const float* __restrict__ bias, float* __restrict__ out)
{
    __shared__ __align__(16) __bf16 sA[2 * 2 * 64 * 32];    // 16 KB
    __shared__ __align__(16) __bf16 sB[2 * 2 * 128 * 32];   // 32 KB
    const int tid  = threadIdx.x;
    const int tm   = blockIdx.y * 64, tn = blockIdx.x * 128;
    const int wave = tid >> 6, lane = tid & 63, quad = lane >> 4, l15 = lane & 15;
    const int wm   = (wave >> 1) * 32, wn = (wave & 1) * 64;

    f32x4 acc[2][4] = {};

    const int e  = tid * 8;
    const int r0 = e >> 5;                // stage row 0..63
    const int cc = e & 31;                // stage col granule {0,8,16,24}

    const int NT = DFF_ / 64;             // 64 K-tiles

    // prologue: stage tile 0 into buf 0
    #pragma unroll
    for (int s = 0; s < 2; ++s) {
        async_ld16(A + (long)(tm + r0) * DFF_ + s * 32 + cc,
                   (void*)(sA + s * 2048 + e));
        #pragma unroll
        for (int q = 0; q < 2; ++q)
            async_ld16(Bw + (long)(tn + q * 64 + r0) * DFF_ + s * 32 + cc,
                       (void*)(sB + s * 4096 + q * 2048 + e));
    }
    __syncthreads();

    int cur = 0;
    for (int t = 0; t < NT; ++t) {
        if (t + 1 < NT) {                 // stage next tile EARLY (other buf)
            const int kk = (t + 1) * 64;
            const int na = (cur ^ 1) * 4096;
            const int nb = (cur ^ 1) * 8192;
            #pragma unroll
            for (int s = 0; s < 2; ++s) {
                async_ld16(A + (long)(tm + r0) * DFF_ + kk + s * 32 + cc,
                           (void*)(sA + na + s * 2048 + e));
                #pragma unroll
                for (int q = 0; q < 2; ++q)
                    async_ld16(Bw + (long)(tn + q * 64 + r0) * DFF_ + kk + s * 32 + cc,
                               (void*)(sB + nb + s * 4096 + q * 2048 + e));
            }
        }
        const int ca = cur * 4096, cb = cur * 8192;
        #pragma unroll
        for (int s = 0; s < 2; ++s) {
            bf16x8 af[2], bf[4];
            #pragma unroll
            for (int i = 0; i < 2; ++i)
                af[i] = *(const bf16x8*)(sA + ca + s * 2048 + (wm + i * 16 + l15) * 32 + quad * 8);
            #pragma unroll
            for (int j = 0; j < 4; ++j)
                bf[j] = *(const bf16x8*)(sB + cb + s * 4096 + (wn + j * 16 + l15) * 32 + quad * 8);
            #pragma unroll
            for (int i = 0; i < 2; ++i)
                #pragma unroll
                for (int j = 0; j < 4; ++j)
                    acc[i][j] = __builtin_amdgcn_mfma_f32_16x16x32_bf16(af[i], bf[j], acc[i][j], 0, 0, 0);
        }
        __syncthreads();                  // drains staged loads + syncs reads
        cur ^= 1;
    }

    #pragma unroll
    for (int j = 0; j < 4; ++j) {
        const int col = tn + wn + j * 16 + l15;
        const float bj = bias[col];
        #pragma unroll
        for (int i = 0; i < 2; ++i) {
            const int row = tm + wm + i * 16 + quad * 4;
            #pragma unroll
            for (int r = 0; r < 4; ++r)
                out[(long)(row + r) * 1024 + col] = acc[i][j][r] + bj;
        }
    }
}

// ---------------------------------------------------------------------------
extern "C" void kernel_launch(void* const* d_in, const int* in_sizes, int n_in,
                              void* d_out, int out_size, void* d_ws, size_t ws_size,
                              hipStream_t stream) {
    const float* x    = (const float*)d_in[0];
    const int*   sel  = (const int*)  d_in[1];
    const float* pw   = (const float*)d_in[2];
    const float* bp   = (const float*)d_in[3];
    const float* cm_w = (const float*)d_in[4];
    const float* cm_b = (const float*)d_in[5];
    const float* adj  = (const float*)d_in[6];
    const float* w2   = (const float*)d_in[7];
    const float* w2b  = (const float*)d_in[8];
    float* out = (float*)d_out;

    // ws: [0,8M) x_bf | [8M,32M) Yp1..Yp3 (both dead once act is written)
    //     [0,32M) act | [32M,37M) P | [37M,45M) w2bf | [45M,..) bins
    char* ws = (char*)d_ws;
    __bf16* x_bf = (__bf16*)ws;
    __bf16* act  = (__bf16*)ws;
    float*  Yp1  = (float*)(ws + (size_t) 8 * 1024 * 1024);
    float*  Yp2  = (float*)(ws + (size_t)16 * 1024 * 1024);
    float*  Yp3  = (float*)(ws + (size_t)24 * 1024 * 1024);
    __bf16* P    = (__bf16*)(ws + (size_t)32 * 1024 * 1024);
    __bf16* w2bf = (__bf16*)(ws + (size_t)37 * 1024 * 1024);
    char*  bins  = ws + (size_t)45 * 1024 * 1024;
    int* bucket  = (int*)bins;                 // 131072 B
    int* rank    = (int*)(bins + 131072);      // 131072 B
    int* counts  = (int*)(bins + 262144);      // 2048 B
    int* cursor  = (int*)(bins + 264192);      // 2048 B
    int* offsets = (int*)(bins + 266240);      // 2052 B

    // d_out staging (consumed before k_outgemm): Yp0 f32 8M | Wd 4.72M
    float*  Yp0 = (float*)d_out;
    __bf16* Wd  = (__bf16*)((char*)d_out + (size_t)8 * 1024 * 1024);

    hipMemsetAsync(counts, 0, 4096, stream);   // counts + cursor
    k_hist   <<<128, 256, 0, stream>>>(sel, counts);
    k_scan   <<<1,   512, 0, stream>>>(counts, offsets, cursor);
    k_scatter<<<128, 256, 0, stream>>>(sel, cursor, bucket, rank);
    k_cvt    <<<1024, 256, 0, stream>>>(x, x_bf, T_ * DM_ / 16);
    k_selmod <<<dim3(POOL_, 4), 256, 0, stream>>>(x_bf, cm_w, bucket, offsets,
                                                  Yp0, Yp1, Yp2, Yp3);
    k_wdense <<<T_ / 4, 256, 0, stream>>>(Yp0, Yp1, Yp2, Yp3, sel, rank, pw, cm_b, Wd);
    k_buildP <<<dim3(9, 64), 256, 0, stream>>>(bp, adj, P);
    k_cvt    <<<1024, 256, 0, stream>>>(w2, w2bf, DM_ * DFF_ / 16);
    k_actgemm<<<dim3(DFF_ / 128, T_ / 128), 256, 0, stream>>>(Wd, P, act);
    k_outgemm<<<dim3(DM_ / 128, T_ / 64), 256, 0, stream>>>(act, w2bf, w2b, out);
}